// Round 5
// baseline (220.033 us; speedup 1.0000x reference)
//
#include <hip/hip_runtime.h>
#include <cstdint>

#define BB 4
#define CC 1024
#define DD 1024
#define HH 16
#define HD 64
#define NH3 3072

typedef __attribute__((ext_vector_type(8))) short short8;   // 8 x bf16 (4 VGPRs)
typedef __attribute__((ext_vector_type(4))) float f32x4;

#define MFMA16(a, b, c) __builtin_amdgcn_mfma_f32_16x16x32_bf16(a, b, c, 0, 0, 0)
#define EXP2 __builtin_amdgcn_exp2f

// async global->LDS, 16B per lane; LDS dest = uniform base + lane*16
__device__ __forceinline__ void glds16(const void* g, void* l) {
    __builtin_amdgcn_global_load_lds(
        (const __attribute__((address_space(1))) void*)g,
        (__attribute__((address_space(3))) void*)l, 16, 0, 0);
}

__device__ __forceinline__ ushort f2bf(float f) {
    union { float f; uint32_t u; } v; v.f = f;
    uint32_t r = v.u + 0x7FFF + ((v.u >> 16) & 1);   // round-to-nearest-even
    return (ushort)(r >> 16);
}

// pack two fp32 -> bf16x2 via v_perm_b32 (5 instr)
__device__ __forceinline__ uint32_t pack2bf(float a, float b) {
    uint32_t ua = __float_as_uint(a), ub = __float_as_uint(b);
    ua += 0x7FFF + ((ua >> 16) & 1);
    ub += 0x7FFF + ((ub >> 16) & 1);
    return __builtin_amdgcn_perm(ua, ub, 0x03020706);  // lo16=bf(a), hi16=bf(b)
}

// ---------------------------------------------------------------------------
// prep: fused x->bf16 convert + w_qkv^T + w_proj^T (one launch)
// ---------------------------------------------------------------------------
__global__ __launch_bounds__(256)
void prep_kernel(const float* __restrict__ x, ushort* __restrict__ xbf,
                 const float* __restrict__ wqkv, ushort* __restrict__ wqkvT,
                 const float* __restrict__ wprj, ushort* __restrict__ wprjT)
{
    __shared__ float Ts[64 * 65];
    const int blk = blockIdx.x;
    const int t = threadIdx.x;

    if (blk < 4096) {
        int i = blk * 256 + t;
        float4 v = ((const float4*)x)[i];
        ushort4 o;
        o.x = f2bf(v.x); o.y = f2bf(v.y); o.z = f2bf(v.z); o.w = f2bf(v.w);
        ((ushort4*)xbf)[i] = o;
        return;
    }

    const float* in; ushort* outp; int K, N, n0, k0;
    if (blk < 4864) {
        int bx = blk - 4096;
        in = wqkv; outp = wqkvT; K = DD; N = NH3;
        n0 = (bx % 48) * 64; k0 = (bx / 48) * 64;
    } else {
        int bx = blk - 4864;
        in = wprj; outp = wprjT; K = DD; N = DD;
        n0 = (bx % 16) * 64; k0 = (bx / 16) * 64;
    }
    #pragma unroll
    for (int i = 0; i < 16; ++i) {
        int idx = t + i * 256;
        int r = idx >> 6, c = idx & 63;
        Ts[r * 65 + c] = in[(size_t)(k0 + r) * N + n0 + c];
    }
    __syncthreads();
    #pragma unroll
    for (int i = 0; i < 16; ++i) {
        int idx = t + i * 256;
        int rr = idx >> 6, cc = idx & 63;
        outp[(size_t)(n0 + rr) * K + k0 + cc] = f2bf(Ts[cc * 65 + rr]);
    }
}

// ---------------------------------------------------------------------------
// bf16 MFMA GEMM (unchanged from R4): 128x128 tile, BK=32, LDS double-buffer.
// ---------------------------------------------------------------------------
template<int MODE>
__global__ __launch_bounds__(256)
void gemm_bt(const ushort* __restrict__ A, const ushort* __restrict__ Bt,
             const float* __restrict__ bias, float* __restrict__ Cf,
             ushort* __restrict__ qb, ushort* __restrict__ kb, ushort* __restrict__ vtb,
             int M, int N, int K)
{
    __shared__ ushort As[2][128 * 32];
    __shared__ ushort Bs[2][128 * 32];

    const int tid = threadIdx.x;
    const int wid = tid >> 6, lane = tid & 63;
    const int quad = lane >> 4, l15 = lane & 15;
    const int m0 = blockIdx.y * 128, n0 = blockIdx.x * 128;
    const int wm = (wid >> 1) * 64, wn = (wid & 1) * 64;

    const int sr = lane >> 2;
    const int sc = lane & 3;

    const int r0 = wid * 32 + sr;
    const int cg0 = sc ^ ((r0 >> 1) & 3);
    const int cg1 = sc ^ (((r0 + 16) >> 1) & 3);
    const ushort* Ar0 = A  + (size_t)(m0 + r0) * K + cg0 * 8;
    const ushort* Ar1 = A  + (size_t)(m0 + r0 + 16) * K + cg1 * 8;
    const ushort* Br0 = Bt + (size_t)(n0 + r0) * K + cg0 * 8;
    const ushort* Br1 = Bt + (size_t)(n0 + r0 + 16) * K + cg1 * 8;

    f32x4 acc[4][4];
    #pragma unroll
    for (int i = 0; i < 4; ++i)
        #pragma unroll
        for (int j = 0; j < 4; ++j) acc[i][j] = (f32x4)(0.0f);

    glds16(Ar0, &As[0][(wid * 32) * 32]);
    glds16(Br0, &Bs[0][(wid * 32) * 32]);
    glds16(Ar1, &As[0][(wid * 32 + 16) * 32]);
    glds16(Br1, &Bs[0][(wid * 32 + 16) * 32]);

    int buf = 0;
    for (int k0 = 0; k0 < K; k0 += 32) {
        __syncthreads();
        if (k0 + 32 < K) {
            const int kn = k0 + 32;
            glds16(Ar0 + kn, &As[buf ^ 1][(wid * 32) * 32]);
            glds16(Br0 + kn, &Bs[buf ^ 1][(wid * 32) * 32]);
            glds16(Ar1 + kn, &As[buf ^ 1][(wid * 32 + 16) * 32]);
            glds16(Br1 + kn, &Bs[buf ^ 1][(wid * 32 + 16) * 32]);
        }

        short8 af[4], bf[4];
        #pragma unroll
        for (int i = 0; i < 4; ++i) {
            int row = wm + i * 16 + l15;
            af[i] = *(const short8*)(&As[buf][row * 32 + (quad ^ ((row >> 1) & 3)) * 8]);
            int col = wn + i * 16 + l15;
            bf[i] = *(const short8*)(&Bs[buf][col * 32 + (quad ^ ((col >> 1) & 3)) * 8]);
        }
        #pragma unroll
        for (int i = 0; i < 4; ++i)
            #pragma unroll
            for (int j = 0; j < 4; ++j)
                acc[i][j] = MFMA16(af[i], bf[j], acc[i][j]);
        buf ^= 1;
    }

    if (MODE == 0) {
        #pragma unroll
        for (int i = 0; i < 4; ++i) {
            int row = m0 + wm + i * 16 + quad * 4;
            #pragma unroll
            for (int j = 0; j < 4; ++j) {
                int col = n0 + wn + j * 16 + l15;
                float bv = bias[col];
                #pragma unroll
                for (int r = 0; r < 4; ++r)
                    Cf[(size_t)(row + r) * N + col] = acc[i][j][r] + bv;
            }
        }
    } else {
        #pragma unroll
        for (int j = 0; j < 4; ++j) {
            int n = n0 + wn + j * 16 + l15;
            int three = n >> 10;
            int h = (n >> 6) & 15;
            int hd = n & 63;
            float scale = (three == 0) ? 0.1803368801f : 1.0f;  // 0.125*log2(e)
            float bv = bias[n];
            #pragma unroll
            for (int i = 0; i < 4; ++i) {
                int row = m0 + wm + i * 16 + quad * 4;
                #pragma unroll
                for (int r = 0; r < 4; ++r) {
                    int m = row + r;
                    int b = m >> 10, c = m & 1023;
                    ushort val = f2bf((acc[i][j][r] + bv) * scale);
                    if (three == 0)
                        qb[((size_t)((b * HH + h) * CC) + c) * HD + hd] = val;
                    else if (three == 1)
                        kb[((size_t)((b * HH + h) * CC) + c) * HD + hd] = val;
                    else
                        vtb[((size_t)((b * HH + h) * HD) + hd) * CC + c] = val;
                }
            }
        }
    }
}

// ---------------------------------------------------------------------------
// Flash attention v4: software-pipelined. Iteration kt runs S_kt and PV_{kt-1}
// as independent MFMA streams; exp/pack chain of tile kt overlaps PV MFMAs.
// Ks[2] (prefetch kt+1), Vs[2] delayed (stage V_kt at iter kt, consume kt+1),
// Ps[2] (write P_kt, read P_{kt-1}). Fast exp2 + v_perm bf16 packing.
// ---------------------------------------------------------------------------
__global__ __launch_bounds__(256)
void attn_mfma4(const ushort* __restrict__ qb, const ushort* __restrict__ kb,
                const ushort* __restrict__ vt, ushort* __restrict__ attnb)
{
    __shared__ ushort Ks[2][64 * 64];   // [key][hd] chunk-swizzled (2 x 8 KB)
    __shared__ ushort Vs[2][64 * 64];   // [hd][key] = V^T        (2 x 8 KB)
    __shared__ ushort Ps[2][128 * 72];  // [qrow][key], pitch 72  (2 x 18 KB)

    const int tid = threadIdx.x;
    const int wid = tid >> 6, lane = tid & 63;
    const int quad = lane >> 4, l15 = lane & 15;
    const int qt = blockIdx.x, bh = blockIdx.y;
    const int q0 = qt * 128;
    const int b = bh >> 4, h = bh & 15;

    const ushort* Qp  = qb + ((size_t)bh * CC + q0) * HD;
    const ushort* Kp  = kb + (size_t)bh * CC * HD;
    const ushort* Vtp = vt + (size_t)bh * HD * CC;

    const int sr = lane >> 3;    // 0..7
    const int sc = lane & 7;     // chunk 0..7

    // Q fragments straight from global: B-operand [n=qrow][k=d], kt-invariant
    short8 qf[2][2];
    #pragma unroll
    for (int q2 = 0; q2 < 2; ++q2) {
        int row = wid * 32 + q2 * 16 + l15;
        #pragma unroll
        for (int s = 0; s < 2; ++s)
            qf[q2][s] = *(const short8*)(Qp + (size_t)row * HD + (s * 4 + quad) * 8);
    }

    // staging addresses (kt-invariant parts)
    const int kr = wid * 16 + sr;            // rows kr, kr+8
    const int cgA = sc ^ (kr & 7);
    const int cgB = sc ^ ((kr + 8) & 7);
    const ushort* Kr0 = Kp  + (size_t)kr * HD + cgA * 8;
    const ushort* Kr1 = Kp  + (size_t)(kr + 8) * HD + cgB * 8;
    const ushort* Vr0 = Vtp + (size_t)kr * CC + cgA * 8;
    const ushort* Vr1 = Vtp + (size_t)(kr + 8) * CC + cgB * 8;

    // prologue: K tile 0 -> Ks[0]
    glds16(Kr0, &Ks[0][(wid * 16) * 64]);
    glds16(Kr1, &Ks[0][(wid * 16 + 8) * 64]);

    f32x4 oacc[2][4];
    #pragma unroll
    for (int q2 = 0; q2 < 2; ++q2)
        #pragma unroll
        for (int hb = 0; hb < 4; ++hb) oacc[q2][hb] = (f32x4)(0.0f);
    float lsum[2] = {0.0f, 0.0f};

    #pragma unroll
    for (int kt = 0; kt < 16; ++kt) {
        const int cur = kt & 1, prev = (kt - 1) & 1, nxt = (kt + 1) & 1;
        __syncthreads();   // K_kt (and V_{kt-1}, staged last iter) now resident
        if (kt < 15) {     // prefetch K_{kt+1}
            const size_t ko = (size_t)(kt + 1) * 64 * HD;
            glds16(Kr0 + ko, &Ks[nxt][(wid * 16) * 64]);
            glds16(Kr1 + ko, &Ks[nxt][(wid * 16 + 8) * 64]);
        }
        {                  // stage V_kt (consumed at iter kt+1)
            const int vo = kt * 64;
            glds16(Vr0 + vo, &Vs[cur][(wid * 16) * 64]);
            glds16(Vr1 + vo, &Vs[cur][(wid * 16 + 8) * 64]);
        }

        if (kt > 0) {
            // PV_{kt-1}: O += P_{kt-1} @ V_{kt-1}
            short8 vf[4][2];
            #pragma unroll
            for (int hb = 0; hb < 4; ++hb) {
                int hr = hb * 16 + l15;
                vf[hb][0] = *(const short8*)(&Vs[prev][hr * 64 + ((quad ^ (hr & 7)) * 8)]);
                vf[hb][1] = *(const short8*)(&Vs[prev][hr * 64 + (((4 + quad) ^ (hr & 7)) * 8)]);
            }
            #pragma unroll
            for (int q2 = 0; q2 < 2; ++q2) {
                int row = wid * 32 + q2 * 16 + l15;
                short8 pf0 = *(const short8*)(&Ps[prev][row * 72 + quad * 8]);
                short8 pf1 = *(const short8*)(&Ps[prev][row * 72 + 32 + quad * 8]);
                #pragma unroll
                for (int hb = 0; hb < 4; ++hb) {
                    oacc[q2][hb] = MFMA16(pf0, vf[hb][0], oacc[q2][hb]);
                    oacc[q2][hb] = MFMA16(pf1, vf[hb][1], oacc[q2][hb]);
                }
            }
        }

        // S_kt = (K Q^T): lane holds S[qrow=l15][key=kb2*16+quad*4+r]
        #pragma unroll
        for (int kb2 = 0; kb2 < 4; ++kb2) {
            int krow = kb2 * 16 + l15;
            short8 kf0 = *(const short8*)(&Ks[cur][krow * 64 + ((quad ^ (krow & 7)) * 8)]);
            short8 kf1 = *(const short8*)(&Ks[cur][krow * 64 + (((4 + quad) ^ (krow & 7)) * 8)]);
            #pragma unroll
            for (int q2 = 0; q2 < 2; ++q2) {
                f32x4 st = (f32x4)(0.0f);
                st = MFMA16(kf0, qf[q2][0], st);
                st = MFMA16(kf1, qf[q2][1], st);
                float p0 = EXP2(st[0]);
                float p1 = EXP2(st[1]);
                float p2 = EXP2(st[2]);
                float p3 = EXP2(st[3]);
                lsum[q2] += (p0 + p1) + (p2 + p3);
                int row = wid * 32 + q2 * 16 + l15;
                *(uint2*)(&Ps[cur][row * 72 + kb2 * 16 + quad * 4]) =
                    make_uint2(pack2bf(p0, p1), pack2bf(p2, p3));
            }
        }
    }

    // final PV_15 (P in Ps[1], V_15 in Vs[1], staged at iter 15)
    __syncthreads();
    {
        short8 vf[4][2];
        #pragma unroll
        for (int hb = 0; hb < 4; ++hb) {
            int hr = hb * 16 + l15;
            vf[hb][0] = *(const short8*)(&Vs[1][hr * 64 + ((quad ^ (hr & 7)) * 8)]);
            vf[hb][1] = *(const short8*)(&Vs[1][hr * 64 + (((4 + quad) ^ (hr & 7)) * 8)]);
        }
        #pragma unroll
        for (int q2 = 0; q2 < 2; ++q2) {
            int row = wid * 32 + q2 * 16 + l15;
            short8 pf0 = *(const short8*)(&Ps[1][row * 72 + quad * 8]);
            short8 pf1 = *(const short8*)(&Ps[1][row * 72 + 32 + quad * 8]);
            #pragma unroll
            for (int hb = 0; hb < 4; ++hb) {
                oacc[q2][hb] = MFMA16(pf0, vf[hb][0], oacc[q2][hb]);
                oacc[q2][hb] = MFMA16(pf1, vf[hb][1], oacc[q2][hb]);
            }
        }
    }

    // reduce lsum across the 4 quads (lanes sharing l15)
    #pragma unroll
    for (int q2 = 0; q2 < 2; ++q2) {
        lsum[q2] += __shfl_xor(lsum[q2], 16);
        lsum[q2] += __shfl_xor(lsum[q2], 32);
    }

    #pragma unroll
    for (int q2 = 0; q2 < 2; ++q2) {
        #pragma unroll
        for (int r = 0; r < 4; ++r) {
            float inv = 1.0f / __shfl(lsum[q2], (lane & 48) | (quad * 4 + r));
            int c = q0 + wid * 32 + q2 * 16 + quad * 4 + r;
            #pragma unroll
            for (int hb = 0; hb < 4; ++hb) {
                int d = h * 64 + hb * 16 + l15;
                attnb[((size_t)(b * CC + c)) * DD + d] = f2bf(oacc[q2][hb][r] * inv);
            }
        }
    }
}

// ---------------------------------------------------------------------------
extern "C" void kernel_launch(void* const* d_in, const int* in_sizes, int n_in,
                              void* d_out, int out_size, void* d_ws, size_t ws_size,
                              hipStream_t stream)
{
    (void)in_sizes; (void)n_in; (void)out_size; (void)ws_size;
    const float* x      = (const float*)d_in[0];
    const float* w_qkv  = (const float*)d_in[1];
    const float* b_qkv  = (const float*)d_in[2];
    const float* w_proj = (const float*)d_in[3];
    const float* b_proj = (const float*)d_in[4];
    float* out = (float*)d_out;

    ushort* p = (ushort*)d_ws;
    ushort* xbf   = p;  p += (size_t)4 * 1024 * 1024;   // x bf16
    ushort* wqkvT = p;  p += (size_t)3 * 1024 * 1024;   // w_qkv^T bf16
    ushort* wprjT = p;  p += (size_t)1 * 1024 * 1024;   // w_proj^T bf16
    ushort* qbuf  = p;  p += (size_t)4 * 1024 * 1024;   // Q (B,H,C,Hd), pre-scaled
    ushort* kbuf  = p;  p += (size_t)4 * 1024 * 1024;   // K (B,H,C,Hd)
    ushort* vtb   = p;  p += (size_t)4 * 1024 * 1024;   // V^T (B,H,Hd,C)
    ushort* attnb = p;  p += (size_t)4 * 1024 * 1024;   // attention out (B,C,D)

    prep_kernel<<<5120, 256, 0, stream>>>(x, xbf, w_qkv, wqkvT, w_proj, wprjT);

    gemm_bt<1><<<dim3(NH3 / 128, (BB * CC) / 128), 256, 0, stream>>>(
        xbf, wqkvT, b_qkv, nullptr, qbuf, kbuf, vtb, BB * CC, NH3, DD);

    attn_mfma4<<<dim3(8, 64), 256, 0, stream>>>(qbuf, kbuf, vtb, attnb);

    gemm_bt<0><<<dim3(DD / 128, (BB * CC) / 128), 256, 0, stream>>>(
        attnb, wprjT, b_proj, out, nullptr, nullptr, nullptr, BB * CC, DD, DD);
}

// Round 6
// 182.361 us; speedup vs baseline: 1.2066x; 1.2066x over previous
//
#include <hip/hip_runtime.h>
#include <cstdint>

#define BB 4
#define CC 1024
#define DD 1024
#define HH 16
#define HD 64
#define NH3 3072

typedef __attribute__((ext_vector_type(8))) short short8;   // 8 x bf16 (4 VGPRs)
typedef __attribute__((ext_vector_type(4))) float f32x4;

#define MFMA16(a, b, c) __builtin_amdgcn_mfma_f32_16x16x32_bf16(a, b, c, 0, 0, 0)
#define EXP2 __builtin_amdgcn_exp2f

// async global->LDS, 16B per lane; LDS dest = uniform base + lane*16
__device__ __forceinline__ void glds16(const void* g, void* l) {
    __builtin_amdgcn_global_load_lds(
        (const __attribute__((address_space(1))) void*)g,
        (__attribute__((address_space(3))) void*)l, 16, 0, 0);
}

__device__ __forceinline__ ushort f2bf(float f) {
    union { float f; uint32_t u; } v; v.f = f;
    uint32_t r = v.u + 0x7FFF + ((v.u >> 16) & 1);   // round-to-nearest-even
    return (ushort)(r >> 16);
}

// pack two fp32 -> bf16x2 via v_perm_b32
__device__ __forceinline__ uint32_t pack2bf(float a, float b) {
    uint32_t ua = __float_as_uint(a), ub = __float_as_uint(b);
    ua += 0x7FFF + ((ua >> 16) & 1);
    ub += 0x7FFF + ((ub >> 16) & 1);
    return __builtin_amdgcn_perm(ua, ub, 0x03020706);  // lo16=bf(a), hi16=bf(b)
}

// ---------------------------------------------------------------------------
// prep: fused x->bf16 convert + w_qkv^T + w_proj^T (one launch)
// ---------------------------------------------------------------------------
__global__ __launch_bounds__(256)
void prep_kernel(const float* __restrict__ x, ushort* __restrict__ xbf,
                 const float* __restrict__ wqkv, ushort* __restrict__ wqkvT,
                 const float* __restrict__ wprj, ushort* __restrict__ wprjT)
{
    __shared__ float Ts[64 * 65];
    const int blk = blockIdx.x;
    const int t = threadIdx.x;

    if (blk < 4096) {
        int i = blk * 256 + t;
        float4 v = ((const float4*)x)[i];
        ushort4 o;
        o.x = f2bf(v.x); o.y = f2bf(v.y); o.z = f2bf(v.z); o.w = f2bf(v.w);
        ((ushort4*)xbf)[i] = o;
        return;
    }

    const float* in; ushort* outp; int K, N, n0, k0;
    if (blk < 4864) {
        int bx = blk - 4096;
        in = wqkv; outp = wqkvT; K = DD; N = NH3;
        n0 = (bx % 48) * 64; k0 = (bx / 48) * 64;
    } else {
        int bx = blk - 4864;
        in = wprj; outp = wprjT; K = DD; N = DD;
        n0 = (bx % 16) * 64; k0 = (bx / 16) * 64;
    }
    #pragma unroll
    for (int i = 0; i < 16; ++i) {
        int idx = t + i * 256;
        int r = idx >> 6, c = idx & 63;
        Ts[r * 65 + c] = in[(size_t)(k0 + r) * N + n0 + c];
    }
    __syncthreads();
    #pragma unroll
    for (int i = 0; i < 16; ++i) {
        int idx = t + i * 256;
        int rr = idx >> 6, cc = idx & 63;
        outp[(size_t)(n0 + rr) * K + k0 + cc] = f2bf(Ts[cc * 65 + rr]);
    }
}

// ---------------------------------------------------------------------------
// bf16 MFMA GEMM: 128x128 tile, BK=32, LDS double-buffer (R4-proven).
// ---------------------------------------------------------------------------
template<int MODE>
__global__ __launch_bounds__(256)
void gemm_bt(const ushort* __restrict__ A, const ushort* __restrict__ Bt,
             const float* __restrict__ bias, float* __restrict__ Cf,
             ushort* __restrict__ qb, ushort* __restrict__ kb, ushort* __restrict__ vtb,
             int M, int N, int K)
{
    __shared__ ushort As[2][128 * 32];
    __shared__ ushort Bs[2][128 * 32];

    const int tid = threadIdx.x;
    const int wid = tid >> 6, lane = tid & 63;
    const int quad = lane >> 4, l15 = lane & 15;
    const int m0 = blockIdx.y * 128, n0 = blockIdx.x * 128;
    const int wm = (wid >> 1) * 64, wn = (wid & 1) * 64;

    const int sr = lane >> 2;
    const int sc = lane & 3;

    const int r0 = wid * 32 + sr;
    const int cg0 = sc ^ ((r0 >> 1) & 3);
    const int cg1 = sc ^ (((r0 + 16) >> 1) & 3);
    const ushort* Ar0 = A  + (size_t)(m0 + r0) * K + cg0 * 8;
    const ushort* Ar1 = A  + (size_t)(m0 + r0 + 16) * K + cg1 * 8;
    const ushort* Br0 = Bt + (size_t)(n0 + r0) * K + cg0 * 8;
    const ushort* Br1 = Bt + (size_t)(n0 + r0 + 16) * K + cg1 * 8;

    f32x4 acc[4][4];
    #pragma unroll
    for (int i = 0; i < 4; ++i)
        #pragma unroll
        for (int j = 0; j < 4; ++j) acc[i][j] = (f32x4)(0.0f);

    glds16(Ar0, &As[0][(wid * 32) * 32]);
    glds16(Br0, &Bs[0][(wid * 32) * 32]);
    glds16(Ar1, &As[0][(wid * 32 + 16) * 32]);
    glds16(Br1, &Bs[0][(wid * 32 + 16) * 32]);

    int buf = 0;
    for (int k0 = 0; k0 < K; k0 += 32) {
        __syncthreads();
        if (k0 + 32 < K) {
            const int kn = k0 + 32;
            glds16(Ar0 + kn, &As[buf ^ 1][(wid * 32) * 32]);
            glds16(Br0 + kn, &Bs[buf ^ 1][(wid * 32) * 32]);
            glds16(Ar1 + kn, &As[buf ^ 1][(wid * 32 + 16) * 32]);
            glds16(Br1 + kn, &Bs[buf ^ 1][(wid * 32 + 16) * 32]);
        }

        short8 af[4], bf[4];
        #pragma unroll
        for (int i = 0; i < 4; ++i) {
            int row = wm + i * 16 + l15;
            af[i] = *(const short8*)(&As[buf][row * 32 + (quad ^ ((row >> 1) & 3)) * 8]);
            int col = wn + i * 16 + l15;
            bf[i] = *(const short8*)(&Bs[buf][col * 32 + (quad ^ ((col >> 1) & 3)) * 8]);
        }
        #pragma unroll
        for (int i = 0; i < 4; ++i)
            #pragma unroll
            for (int j = 0; j < 4; ++j)
                acc[i][j] = MFMA16(af[i], bf[j], acc[i][j]);
        buf ^= 1;
    }

    if (MODE == 0) {
        #pragma unroll
        for (int i = 0; i < 4; ++i) {
            int row = m0 + wm + i * 16 + quad * 4;
            #pragma unroll
            for (int j = 0; j < 4; ++j) {
                int col = n0 + wn + j * 16 + l15;
                float bv = bias[col];
                #pragma unroll
                for (int r = 0; r < 4; ++r)
                    Cf[(size_t)(row + r) * N + col] = acc[i][j][r] + bv;
            }
        }
    } else {
        #pragma unroll
        for (int j = 0; j < 4; ++j) {
            int n = n0 + wn + j * 16 + l15;
            int three = n >> 10;
            int h = (n >> 6) & 15;
            int hd = n & 63;
            float scale = (three == 0) ? 0.1803368801f : 1.0f;  // 0.125*log2(e)
            float bv = bias[n];
            #pragma unroll
            for (int i = 0; i < 4; ++i) {
                int row = m0 + wm + i * 16 + quad * 4;
                #pragma unroll
                for (int r = 0; r < 4; ++r) {
                    int m = row + r;
                    int b = m >> 10, c = m & 1023;
                    ushort val = f2bf((acc[i][j][r] + bv) * scale);
                    if (three == 0)
                        qb[((size_t)((b * HH + h) * CC) + c) * HD + hd] = val;
                    else if (three == 1)
                        kb[((size_t)((b * HH + h) * CC) + c) * HD + hd] = val;
                    else
                        vtb[((size_t)((b * HH + h) * HD) + hd) * CC + c] = val;
                }
            }
        }
    }
}

// ---------------------------------------------------------------------------
// Flash attention v5 = R4's proven attn_mfma3 structure (68 VGPR, no spill)
// + fast v_exp_f32 + v_perm bf16 pack + bh-fastest 1-D grid so the 8 q-tile
// blocks sharing one bh's K/V colocate on one XCD (L2 reuse).
// ---------------------------------------------------------------------------
__global__ __launch_bounds__(256)
void attn_mfma5(const ushort* __restrict__ qb, const ushort* __restrict__ kb,
                const ushort* __restrict__ vt, ushort* __restrict__ attnb)
{
    __shared__ ushort Ks[2][64 * 64];   // [key][hd] chunk-swizzled (2 x 8 KB)
    __shared__ ushort Vs[2][64 * 64];   // [hd][key] = V^T        (2 x 8 KB)
    __shared__ ushort Ps[128 * 72];     // [qrow][key], pitch 72  (18 KB)

    const int tid = threadIdx.x;
    const int wid = tid >> 6, lane = tid & 63;
    const int quad = lane >> 4, l15 = lane & 15;
    // bh-fastest: blocks 0..63 = qt0 for all bh -> same-bh q-tiles share XCD
    const int bh = blockIdx.x & 63;
    const int qt = blockIdx.x >> 6;
    const int q0 = qt * 128;
    const int b = bh >> 4, h = bh & 15;

    const ushort* Qp  = qb + ((size_t)bh * CC + q0) * HD;
    const ushort* Kp  = kb + (size_t)bh * CC * HD;
    const ushort* Vtp = vt + (size_t)bh * HD * CC;

    const int sr = lane >> 3;    // 0..7
    const int sc = lane & 7;     // chunk 0..7

    // Q fragments straight from global: B-operand [n=qrow][k=d], kt-invariant
    short8 qf[2][2];
    #pragma unroll
    for (int q2 = 0; q2 < 2; ++q2) {
        int row = wid * 32 + q2 * 16 + l15;
        #pragma unroll
        for (int s = 0; s < 2; ++s)
            qf[q2][s] = *(const short8*)(Qp + (size_t)row * HD + (s * 4 + quad) * 8);
    }

    // staging addresses (kt-invariant parts)
    const int kr = wid * 16 + sr;            // rows kr, kr+8
    const int cgA = sc ^ (kr & 7);
    const int cgB = sc ^ ((kr + 8) & 7);
    const ushort* Kr0 = Kp  + (size_t)kr * HD + cgA * 8;
    const ushort* Kr1 = Kp  + (size_t)(kr + 8) * HD + cgB * 8;
    const ushort* Vr0 = Vtp + (size_t)kr * CC + cgA * 8;
    const ushort* Vr1 = Vtp + (size_t)(kr + 8) * CC + cgB * 8;

    // prologue: stage K/V tile 0 into buf 0
    glds16(Kr0, &Ks[0][(wid * 16) * 64]);
    glds16(Vr0, &Vs[0][(wid * 16) * 64]);
    glds16(Kr1, &Ks[0][(wid * 16 + 8) * 64]);
    glds16(Vr1, &Vs[0][(wid * 16 + 8) * 64]);

    f32x4 oacc[2][4];
    #pragma unroll
    for (int q2 = 0; q2 < 2; ++q2)
        #pragma unroll
        for (int hb = 0; hb < 4; ++hb) oacc[q2][hb] = (f32x4)(0.0f);
    float lsum[2] = {0.0f, 0.0f};

    int buf = 0;
    for (int kt = 0; kt < 16; ++kt) {
        __syncthreads();                      // tile kt ready in buf
        if (kt < 15) {                        // prefetch kt+1 into buf^1
            const int koff = (kt + 1) * 64;
            glds16(Kr0 + (size_t)koff * HD, &Ks[buf ^ 1][(wid * 16) * 64]);
            glds16(Vr0 + koff,              &Vs[buf ^ 1][(wid * 16) * 64]);
            glds16(Kr1 + (size_t)koff * HD, &Ks[buf ^ 1][(wid * 16 + 8) * 64]);
            glds16(Vr1 + koff,              &Vs[buf ^ 1][(wid * 16 + 8) * 64]);
        }

        // S^T = K @ Q^T : lane holds S[qrow=l15][key=kb2*16+quad*4+r]
        #pragma unroll
        for (int kb2 = 0; kb2 < 4; ++kb2) {
            int krow = kb2 * 16 + l15;
            short8 kf0 = *(const short8*)(&Ks[buf][krow * 64 + ((quad ^ (krow & 7)) * 8)]);
            short8 kf1 = *(const short8*)(&Ks[buf][krow * 64 + (((4 + quad) ^ (krow & 7)) * 8)]);
            #pragma unroll
            for (int q2 = 0; q2 < 2; ++q2) {
                f32x4 st = (f32x4)(0.0f);
                st = MFMA16(kf0, qf[q2][0], st);
                st = MFMA16(kf1, qf[q2][1], st);
                float p0 = EXP2(st[0]);
                float p1 = EXP2(st[1]);
                float p2 = EXP2(st[2]);
                float p3 = EXP2(st[3]);
                lsum[q2] += (p0 + p1) + (p2 + p3);
                int row = wid * 32 + q2 * 16 + l15;
                *(uint2*)(Ps + row * 72 + kb2 * 16 + quad * 4) =
                    make_uint2(pack2bf(p0, p1), pack2bf(p2, p3));
            }
        }

        // O += P @ V  (wave-private P rows; no cross-wave barrier needed)
        short8 vf[4][2];
        #pragma unroll
        for (int hb = 0; hb < 4; ++hb) {
            int hr = hb * 16 + l15;
            vf[hb][0] = *(const short8*)(&Vs[buf][hr * 64 + ((quad ^ (hr & 7)) * 8)]);
            vf[hb][1] = *(const short8*)(&Vs[buf][hr * 64 + (((4 + quad) ^ (hr & 7)) * 8)]);
        }
        #pragma unroll
        for (int q2 = 0; q2 < 2; ++q2) {
            int row = wid * 32 + q2 * 16 + l15;
            short8 pf0 = *(const short8*)(Ps + row * 72 + quad * 8);
            short8 pf1 = *(const short8*)(Ps + row * 72 + 32 + quad * 8);
            #pragma unroll
            for (int hb = 0; hb < 4; ++hb) {
                oacc[q2][hb] = MFMA16(pf0, vf[hb][0], oacc[q2][hb]);
                oacc[q2][hb] = MFMA16(pf1, vf[hb][1], oacc[q2][hb]);
            }
        }
        buf ^= 1;
    }

    // reduce lsum across the 4 quads (lanes sharing l15)
    #pragma unroll
    for (int q2 = 0; q2 < 2; ++q2) {
        lsum[q2] += __shfl_xor(lsum[q2], 16);
        lsum[q2] += __shfl_xor(lsum[q2], 32);
    }

    #pragma unroll
    for (int q2 = 0; q2 < 2; ++q2) {
        #pragma unroll
        for (int r = 0; r < 4; ++r) {
            float inv = 1.0f / __shfl(lsum[q2], (lane & 48) | (quad * 4 + r));
            int c = q0 + wid * 32 + q2 * 16 + quad * 4 + r;
            #pragma unroll
            for (int hb = 0; hb < 4; ++hb) {
                int d = h * 64 + hb * 16 + l15;
                attnb[((size_t)(b * CC + c)) * DD + d] = f2bf(oacc[q2][hb][r] * inv);
            }
        }
    }
}

// ---------------------------------------------------------------------------
extern "C" void kernel_launch(void* const* d_in, const int* in_sizes, int n_in,
                              void* d_out, int out_size, void* d_ws, size_t ws_size,
                              hipStream_t stream)
{
    (void)in_sizes; (void)n_in; (void)out_size; (void)ws_size;
    const float* x      = (const float*)d_in[0];
    const float* w_qkv  = (const float*)d_in[1];
    const float* b_qkv  = (const float*)d_in[2];
    const float* w_proj = (const float*)d_in[3];
    const float* b_proj = (const float*)d_in[4];
    float* out = (float*)d_out;

    ushort* p = (ushort*)d_ws;
    ushort* xbf   = p;  p += (size_t)4 * 1024 * 1024;   // x bf16
    ushort* wqkvT = p;  p += (size_t)3 * 1024 * 1024;   // w_qkv^T bf16
    ushort* wprjT = p;  p += (size_t)1 * 1024 * 1024;   // w_proj^T bf16
    ushort* qbuf  = p;  p += (size_t)4 * 1024 * 1024;   // Q (B,H,C,Hd), pre-scaled
    ushort* kbuf  = p;  p += (size_t)4 * 1024 * 1024;   // K (B,H,C,Hd)
    ushort* vtb   = p;  p += (size_t)4 * 1024 * 1024;   // V^T (B,H,Hd,C)
    ushort* attnb = p;  p += (size_t)4 * 1024 * 1024;   // attention out (B,C,D)

    prep_kernel<<<5120, 256, 0, stream>>>(x, xbf, w_qkv, wqkvT, w_proj, wprjT);

    gemm_bt<1><<<dim3(NH3 / 128, (BB * CC) / 128), 256, 0, stream>>>(
        xbf, wqkvT, b_qkv, nullptr, qbuf, kbuf, vtb, BB * CC, NH3, DD);

    attn_mfma5<<<512, 256, 0, stream>>>(qbuf, kbuf, vtb, attnb);

    gemm_bt<0><<<dim3(DD / 128, (BB * CC) / 128), 256, 0, stream>>>(
        attnb, wprjT, b_proj, out, nullptr, nullptr, nullptr, BB * CC, DD, DD);
}

// Round 7
// 176.354 us; speedup vs baseline: 1.2477x; 1.0341x over previous
//
#include <hip/hip_runtime.h>
#include <cstdint>

#define BB 4
#define CC 1024
#define DD 1024
#define HH 16
#define HD 64
#define NH3 3072

typedef __attribute__((ext_vector_type(8))) short short8;   // 8 x bf16 (4 VGPRs)
typedef __attribute__((ext_vector_type(4))) float f32x4;

#define MFMA16(a, b, c) __builtin_amdgcn_mfma_f32_16x16x32_bf16(a, b, c, 0, 0, 0)
#define EXP2 __builtin_amdgcn_exp2f

// async global->LDS, 16B per lane; LDS dest = uniform base + lane*16
__device__ __forceinline__ void glds16(const void* g, void* l) {
    __builtin_amdgcn_global_load_lds(
        (const __attribute__((address_space(1))) void*)g,
        (__attribute__((address_space(3))) void*)l, 16, 0, 0);
}

__device__ __forceinline__ ushort f2bf(float f) {
    union { float f; uint32_t u; } v; v.f = f;
    uint32_t r = v.u + 0x7FFF + ((v.u >> 16) & 1);   // round-to-nearest-even
    return (ushort)(r >> 16);
}

// pack two fp32 -> bf16x2 via v_perm_b32
__device__ __forceinline__ uint32_t pack2bf(float a, float b) {
    uint32_t ua = __float_as_uint(a), ub = __float_as_uint(b);
    ua += 0x7FFF + ((ua >> 16) & 1);
    ub += 0x7FFF + ((ub >> 16) & 1);
    return __builtin_amdgcn_perm(ua, ub, 0x03020706);  // lo16=bf(a), hi16=bf(b)
}

// ---------------------------------------------------------------------------
// prep: fused x->bf16 convert + w_qkv^T + w_proj^T (one launch)
// ---------------------------------------------------------------------------
__global__ __launch_bounds__(256)
void prep_kernel(const float* __restrict__ x, ushort* __restrict__ xbf,
                 const float* __restrict__ wqkv, ushort* __restrict__ wqkvT,
                 const float* __restrict__ wprj, ushort* __restrict__ wprjT)
{
    __shared__ float Ts[64 * 65];
    const int blk = blockIdx.x;
    const int t = threadIdx.x;

    if (blk < 4096) {
        int i = blk * 256 + t;
        float4 v = ((const float4*)x)[i];
        ushort4 o;
        o.x = f2bf(v.x); o.y = f2bf(v.y); o.z = f2bf(v.z); o.w = f2bf(v.w);
        ((ushort4*)xbf)[i] = o;
        return;
    }

    const float* in; ushort* outp; int K, N, n0, k0;
    if (blk < 4864) {
        int bx = blk - 4096;
        in = wqkv; outp = wqkvT; K = DD; N = NH3;
        n0 = (bx % 48) * 64; k0 = (bx / 48) * 64;
    } else {
        int bx = blk - 4864;
        in = wprj; outp = wprjT; K = DD; N = DD;
        n0 = (bx % 16) * 64; k0 = (bx / 16) * 64;
    }
    #pragma unroll
    for (int i = 0; i < 16; ++i) {
        int idx = t + i * 256;
        int r = idx >> 6, c = idx & 63;
        Ts[r * 65 + c] = in[(size_t)(k0 + r) * N + n0 + c];
    }
    __syncthreads();
    #pragma unroll
    for (int i = 0; i < 16; ++i) {
        int idx = t + i * 256;
        int rr = idx >> 6, cc = idx & 63;
        outp[(size_t)(n0 + rr) * K + k0 + cc] = f2bf(Ts[cc * 65 + rr]);
    }
}

// ---------------------------------------------------------------------------
// bf16 MFMA GEMM: MT x 128 tile, BK=32, LDS double-buffer.
// MT=128: 4 waves in 2x2, wave tile 64x64 (4x4 MFMA).
// MT=64 : 4 waves in 2x2, wave tile 32x64 (2x4 MFMA) -- 2x the blocks (TLP).
// MODE 0: fp32 out + bias.  MODE 1 (MT=128): QKV scatter, V transposed.
// ---------------------------------------------------------------------------
template<int MODE, int MT>
__global__ __launch_bounds__(256)
void gemm_bt(const ushort* __restrict__ A, const ushort* __restrict__ Bt,
             const float* __restrict__ bias, float* __restrict__ Cf,
             ushort* __restrict__ qb, ushort* __restrict__ kb, ushort* __restrict__ vtb,
             int M, int N, int K)
{
    constexpr int MI = MT / 32;               // M-dir MFMA tiles per wave
    __shared__ ushort As[2][MT * 32];
    __shared__ ushort Bs[2][128 * 32];

    const int tid = threadIdx.x;
    const int wid = tid >> 6, lane = tid & 63;
    const int quad = lane >> 4, l15 = lane & 15;
    const int m0 = blockIdx.y * MT, n0 = blockIdx.x * 128;
    const int wm = (wid >> 1) * (MT / 2), wn = (wid & 1) * 64;

    const int sr = lane >> 2;
    const int sc = lane & 3;

    // A staging: wave stages MT/4 rows (16 rows per glds)
    const int ar0 = wid * (MT / 4) + sr;
    const int acg0 = sc ^ ((ar0 >> 1) & 3);
    const int acg1 = sc ^ (((ar0 + 16) >> 1) & 3);
    const ushort* Ar0 = A + (size_t)(m0 + ar0) * K + acg0 * 8;
    const ushort* Ar1 = A + (size_t)(m0 + ar0 + 16) * K + acg1 * 8;   // MT=128 only
    // B staging: 128 rows, 2 glds per wave
    const int br0 = wid * 32 + sr;
    const int bcg0 = sc ^ ((br0 >> 1) & 3);
    const int bcg1 = sc ^ (((br0 + 16) >> 1) & 3);
    const ushort* Br0 = Bt + (size_t)(n0 + br0) * K + bcg0 * 8;
    const ushort* Br1 = Bt + (size_t)(n0 + br0 + 16) * K + bcg1 * 8;

    f32x4 acc[MI][4];
    #pragma unroll
    for (int i = 0; i < MI; ++i)
        #pragma unroll
        for (int j = 0; j < 4; ++j) acc[i][j] = (f32x4)(0.0f);

    glds16(Ar0, &As[0][(wid * (MT / 4)) * 32]);
    glds16(Br0, &Bs[0][(wid * 32) * 32]);
    if (MT == 128) glds16(Ar1, &As[0][(wid * 32 + 16) * 32]);
    glds16(Br1, &Bs[0][(wid * 32 + 16) * 32]);

    int buf = 0;
    for (int k0 = 0; k0 < K; k0 += 32) {
        __syncthreads();
        if (k0 + 32 < K) {
            const int kn = k0 + 32;
            glds16(Ar0 + kn, &As[buf ^ 1][(wid * (MT / 4)) * 32]);
            glds16(Br0 + kn, &Bs[buf ^ 1][(wid * 32) * 32]);
            if (MT == 128) glds16(Ar1 + kn, &As[buf ^ 1][(wid * 32 + 16) * 32]);
            glds16(Br1 + kn, &Bs[buf ^ 1][(wid * 32 + 16) * 32]);
        }

        short8 af[MI], bf[4];
        #pragma unroll
        for (int i = 0; i < MI; ++i) {
            int row = wm + i * 16 + l15;
            af[i] = *(const short8*)(&As[buf][row * 32 + (quad ^ ((row >> 1) & 3)) * 8]);
        }
        #pragma unroll
        for (int j = 0; j < 4; ++j) {
            int col = wn + j * 16 + l15;
            bf[j] = *(const short8*)(&Bs[buf][col * 32 + (quad ^ ((col >> 1) & 3)) * 8]);
        }
        #pragma unroll
        for (int i = 0; i < MI; ++i)
            #pragma unroll
            for (int j = 0; j < 4; ++j)
                acc[i][j] = MFMA16(af[i], bf[j], acc[i][j]);
        buf ^= 1;
    }

    if (MODE == 0) {
        #pragma unroll
        for (int i = 0; i < MI; ++i) {
            int row = m0 + wm + i * 16 + quad * 4;
            #pragma unroll
            for (int j = 0; j < 4; ++j) {
                int col = n0 + wn + j * 16 + l15;
                float bv = bias[col];
                #pragma unroll
                for (int r = 0; r < 4; ++r)
                    Cf[(size_t)(row + r) * N + col] = acc[i][j][r] + bv;
            }
        }
    } else {
        #pragma unroll
        for (int j = 0; j < 4; ++j) {
            int n = n0 + wn + j * 16 + l15;
            int three = n >> 10;
            int h = (n >> 6) & 15;
            int hd = n & 63;
            float scale = (three == 0) ? 0.1803368801f : 1.0f;  // 0.125*log2(e)
            float bv = bias[n];
            #pragma unroll
            for (int i = 0; i < MI; ++i) {
                int row = m0 + wm + i * 16 + quad * 4;
                #pragma unroll
                for (int r = 0; r < 4; ++r) {
                    int m = row + r;
                    int b = m >> 10, c = m & 1023;
                    ushort val = f2bf((acc[i][j][r] + bv) * scale);
                    if (three == 0)
                        qb[((size_t)((b * HH + h) * CC) + c) * HD + hd] = val;
                    else if (three == 1)
                        kb[((size_t)((b * HH + h) * CC) + c) * HD + hd] = val;
                    else
                        vtb[((size_t)((b * HH + h) * HD) + hd) * CC + c] = val;
                }
            }
        }
    }
}

// ---------------------------------------------------------------------------
// Flash attention v6: cross-tile software pipeline, ROLLED loop + LDS-offset
// rotation (R5's idea without the unroll-driven VGPR explosion).
// Iter kt: prefetch K/V_{kt+1}; PV_{kt-1} (independent MFMA stream); S_kt ->
// exp -> pack -> P_kt. K dbuf, V triple-buf, P dbuf (wave-private).
// ---------------------------------------------------------------------------
__global__ __launch_bounds__(256)
void attn_mfma6(const ushort* __restrict__ qb, const ushort* __restrict__ kb,
                const ushort* __restrict__ vt, ushort* __restrict__ attnb)
{
    // one flat LDS pool, rotated via uint offsets (keeps pointer state tiny)
    __shared__ ushort lds[2 * 4096 + 3 * 4096 + 2 * 9216];   // 76 KB
    const uint K0 = 0, K1 = 4096;
    const uint V0 = 8192, V1 = 12288, V2 = 16384;
    const uint P0 = 20480, P1 = 29696;

    const int tid = threadIdx.x;
    const int wid = tid >> 6, lane = tid & 63;
    const int quad = lane >> 4, l15 = lane & 15;
    const int bh = blockIdx.x & 63;          // bh-fastest: XCD L2 locality
    const int qt = blockIdx.x >> 6;
    const int q0 = qt * 128;
    const int b = bh >> 4, h = bh & 15;

    const ushort* Qp  = qb + ((size_t)bh * CC + q0) * HD;
    const ushort* Kp  = kb + (size_t)bh * CC * HD;
    const ushort* Vtp = vt + (size_t)bh * HD * CC;

    const int sr = lane >> 3;    // 0..7
    const int sc = lane & 7;     // chunk 0..7

    // Q fragments straight from global: B-operand [n=qrow][k=d], kt-invariant
    short8 qf[2][2];
    #pragma unroll
    for (int q2 = 0; q2 < 2; ++q2) {
        int row = wid * 32 + q2 * 16 + l15;
        #pragma unroll
        for (int s = 0; s < 2; ++s)
            qf[q2][s] = *(const short8*)(Qp + (size_t)row * HD + (s * 4 + quad) * 8);
    }

    // staging addresses (kt-invariant parts)
    const int kr = wid * 16 + sr;            // rows kr, kr+8
    const int cgA = sc ^ (kr & 7);
    const int cgB = sc ^ ((kr + 8) & 7);
    const ushort* Kr0 = Kp  + (size_t)kr * HD + cgA * 8;
    const ushort* Kr1 = Kp  + (size_t)(kr + 8) * HD + cgB * 8;
    const ushort* Vr0 = Vtp + (size_t)kr * CC + cgA * 8;
    const ushort* Vr1 = Vtp + (size_t)(kr + 8) * CC + cgB * 8;

    const uint stg0 = (wid * 16) * 64;       // LDS staging offsets within a buffer
    const uint stg1 = (wid * 16 + 8) * 64;

    // prologue: K_0 -> K0, V_0 -> V0
    glds16(Kr0, lds + K0 + stg0);
    glds16(Kr1, lds + K0 + stg1);
    glds16(Vr0, lds + V0 + stg0);
    glds16(Vr1, lds + V0 + stg1);

    f32x4 oacc[2][4];
    #pragma unroll
    for (int q2 = 0; q2 < 2; ++q2)
        #pragma unroll
        for (int hb = 0; hb < 4; ++hb) oacc[q2][hb] = (f32x4)(0.0f);
    float lsum[2] = {0.0f, 0.0f};

    uint ksC = K0, ksN = K1;
    uint vsP = V2, vsC = V0, vsN = V1;
    uint psC = P0, psP = P1;

    for (int kt = 0; kt < 16; ++kt) {
        __syncthreads();                      // K_kt, V_kt resident
        if (kt < 15) {                        // prefetch K/V_{kt+1}
            const int koff = (kt + 1) * 64;
            glds16(Kr0 + (size_t)koff * HD, lds + ksN + stg0);
            glds16(Kr1 + (size_t)koff * HD, lds + ksN + stg1);
            glds16(Vr0 + koff,              lds + vsN + stg0);
            glds16(Vr1 + koff,              lds + vsN + stg1);
        }

        if (kt > 0) {
            // PV_{kt-1}: O += P_{kt-1} @ V_{kt-1}  (independent of S_kt)
            short8 vf[4][2];
            #pragma unroll
            for (int hb = 0; hb < 4; ++hb) {
                int hr = hb * 16 + l15;
                vf[hb][0] = *(const short8*)(lds + vsP + hr * 64 + ((quad ^ (hr & 7)) * 8));
                vf[hb][1] = *(const short8*)(lds + vsP + hr * 64 + (((4 + quad) ^ (hr & 7)) * 8));
            }
            #pragma unroll
            for (int q2 = 0; q2 < 2; ++q2) {
                int row = wid * 32 + q2 * 16 + l15;
                short8 pf0 = *(const short8*)(lds + psP + row * 72 + quad * 8);
                short8 pf1 = *(const short8*)(lds + psP + row * 72 + 32 + quad * 8);
                #pragma unroll
                for (int hb = 0; hb < 4; ++hb) {
                    oacc[q2][hb] = MFMA16(pf0, vf[hb][0], oacc[q2][hb]);
                    oacc[q2][hb] = MFMA16(pf1, vf[hb][1], oacc[q2][hb]);
                }
            }
        }

        // S_kt = K @ Q^T : lane holds S[qrow=l15][key=kb2*16+quad*4+r]
        #pragma unroll
        for (int kb2 = 0; kb2 < 4; ++kb2) {
            int krow = kb2 * 16 + l15;
            short8 kf0 = *(const short8*)(lds + ksC + krow * 64 + ((quad ^ (krow & 7)) * 8));
            short8 kf1 = *(const short8*)(lds + ksC + krow * 64 + (((4 + quad) ^ (krow & 7)) * 8));
            #pragma unroll
            for (int q2 = 0; q2 < 2; ++q2) {
                f32x4 st = (f32x4)(0.0f);
                st = MFMA16(kf0, qf[q2][0], st);
                st = MFMA16(kf1, qf[q2][1], st);
                float p0 = EXP2(st[0]);
                float p1 = EXP2(st[1]);
                float p2 = EXP2(st[2]);
                float p3 = EXP2(st[3]);
                lsum[q2] += (p0 + p1) + (p2 + p3);
                int row = wid * 32 + q2 * 16 + l15;
                *(uint2*)(lds + psC + row * 72 + kb2 * 16 + quad * 4) =
                    make_uint2(pack2bf(p0, p1), pack2bf(p2, p3));
            }
        }

        // rotate buffers
        uint t = vsP; vsP = vsC; vsC = vsN; vsN = t;
        t = ksC; ksC = ksN; ksN = t;
        t = psP; psP = psC; psC = t;
    }

    // final PV_15: P_15 at psP, V_15 at vsP (post-rotation); no barrier needed
    {
        short8 vf[4][2];
        #pragma unroll
        for (int hb = 0; hb < 4; ++hb) {
            int hr = hb * 16 + l15;
            vf[hb][0] = *(const short8*)(lds + vsP + hr * 64 + ((quad ^ (hr & 7)) * 8));
            vf[hb][1] = *(const short8*)(lds + vsP + hr * 64 + (((4 + quad) ^ (hr & 7)) * 8));
        }
        #pragma unroll
        for (int q2 = 0; q2 < 2; ++q2) {
            int row = wid * 32 + q2 * 16 + l15;
            short8 pf0 = *(const short8*)(lds + psP + row * 72 + quad * 8);
            short8 pf1 = *(const short8*)(lds + psP + row * 72 + 32 + quad * 8);
            #pragma unroll
            for (int hb = 0; hb < 4; ++hb) {
                oacc[q2][hb] = MFMA16(pf0, vf[hb][0], oacc[q2][hb]);
                oacc[q2][hb] = MFMA16(pf1, vf[hb][1], oacc[q2][hb]);
            }
        }
    }

    // reduce lsum across the 4 quads (lanes sharing l15)
    #pragma unroll
    for (int q2 = 0; q2 < 2; ++q2) {
        lsum[q2] += __shfl_xor(lsum[q2], 16);
        lsum[q2] += __shfl_xor(lsum[q2], 32);
    }

    #pragma unroll
    for (int q2 = 0; q2 < 2; ++q2) {
        #pragma unroll
        for (int r = 0; r < 4; ++r) {
            float inv = 1.0f / __shfl(lsum[q2], (lane & 48) | (quad * 4 + r));
            int c = q0 + wid * 32 + q2 * 16 + quad * 4 + r;
            #pragma unroll
            for (int hb = 0; hb < 4; ++hb) {
                int d = h * 64 + hb * 16 + l15;
                attnb[((size_t)(b * CC + c)) * DD + d] = f2bf(oacc[q2][hb][r] * inv);
            }
        }
    }
}

// ---------------------------------------------------------------------------
extern "C" void kernel_launch(void* const* d_in, const int* in_sizes, int n_in,
                              void* d_out, int out_size, void* d_ws, size_t ws_size,
                              hipStream_t stream)
{
    (void)in_sizes; (void)n_in; (void)out_size; (void)ws_size;
    const float* x      = (const float*)d_in[0];
    const float* w_qkv  = (const float*)d_in[1];
    const float* b_qkv  = (const float*)d_in[2];
    const float* w_proj = (const float*)d_in[3];
    const float* b_proj = (const float*)d_in[4];
    float* out = (float*)d_out;

    ushort* p = (ushort*)d_ws;
    ushort* xbf   = p;  p += (size_t)4 * 1024 * 1024;   // x bf16
    ushort* wqkvT = p;  p += (size_t)3 * 1024 * 1024;   // w_qkv^T bf16
    ushort* wprjT = p;  p += (size_t)1 * 1024 * 1024;   // w_proj^T bf16
    ushort* qbuf  = p;  p += (size_t)4 * 1024 * 1024;   // Q (B,H,C,Hd), pre-scaled
    ushort* kbuf  = p;  p += (size_t)4 * 1024 * 1024;   // K (B,H,C,Hd)
    ushort* vtb   = p;  p += (size_t)4 * 1024 * 1024;   // V^T (B,H,Hd,C)
    ushort* attnb = p;  p += (size_t)4 * 1024 * 1024;   // attention out (B,C,D)

    prep_kernel<<<5120, 256, 0, stream>>>(x, xbf, w_qkv, wqkvT, w_proj, wprjT);

    gemm_bt<1, 128><<<dim3(NH3 / 128, (BB * CC) / 128), 256, 0, stream>>>(
        xbf, wqkvT, b_qkv, nullptr, qbuf, kbuf, vtb, BB * CC, NH3, DD);

    attn_mfma6<<<512, 256, 0, stream>>>(qbuf, kbuf, vtb, attnb);

    // proj: M-tile 64 -> 512 blocks (2 blocks/CU) for latency hiding
    gemm_bt<0, 64><<<dim3(DD / 128, (BB * CC) / 64), 256, 0, stream>>>(
        attnb, wprjT, b_proj, out, nullptr, nullptr, nullptr, BB * CC, DD, DD);
}